// Round 1
// baseline (12933.882 us; speedup 1.0000x reference)
//
#include <hip/hip_runtime.h>

typedef unsigned short u16;
typedef __attribute__((ext_vector_type(8))) short short8v;
typedef __attribute__((ext_vector_type(8))) __bf16 bf16x8;
typedef __attribute__((ext_vector_type(4))) float f32x4;

#define AS1 __attribute__((address_space(1)))
#define AS3 __attribute__((address_space(3)))

// ---------- helpers ----------
__device__ __forceinline__ u16 f2bf(float f) {
  unsigned u = __float_as_uint(f);
  u += 0x7fffu + ((u >> 16) & 1u);   // round-to-nearest-even
  return (u16)(u >> 16);
}
__device__ __forceinline__ float bf2f(u16 h) {
  return __uint_as_float(((unsigned)h) << 16);
}
__device__ __forceinline__ void gload_lds16(const void* g, void* l) {
  __builtin_amdgcn_global_load_lds((const AS1 void*)g, (AS3 void*)l, 16, 0, 0);
}
__device__ __forceinline__ bf16x8 ld8(const u16* p) {
  return __builtin_bit_cast(bf16x8, *reinterpret_cast<const short8v*>(p));
}
__device__ __forceinline__ float sigf(float x) { return 1.0f / (1.0f + __expf(-x)); }

// ---------- setup kernels ----------
// x (f32, 16777216) -> bf16
__global__ __launch_bounds__(256) void k_conv_x(const float* __restrict__ x,
                                                u16* __restrict__ xh) {
  int i = blockIdx.x * 256 + threadIdx.x;          // 4194304 threads, one float4 each
  float4 v = reinterpret_cast<const float4*>(x)[i];
  ushort4 o;
  o.x = f2bf(v.x); o.y = f2bf(v.y); o.z = f2bf(v.z); o.w = f2bf(v.w);
  reinterpret_cast<ushort4*>(xh)[i] = o;
}

// Build gate-interleaved packed weights:
//   n' in [0,4096): d = n'>>11, p = n'&2047, j = p>>2, g = p&3, src = g*512+j
//   wall[n'][k] = bf16(Wx_d[src][k]); whp[n'][k] = bf16(Wh_d[src][k]);
//   bias[n'] = bx_d[src] + bh_d[src]
__global__ __launch_bounds__(256) void k_pack_w(
    const float* __restrict__ Wx_f, const float* __restrict__ Wh_f,
    const float* __restrict__ bx_f, const float* __restrict__ bh_f,
    const float* __restrict__ Wx_b, const float* __restrict__ Wh_b,
    const float* __restrict__ bx_b, const float* __restrict__ bh_b,
    u16* __restrict__ wall, u16* __restrict__ whp, float* __restrict__ bias) {
  int i = blockIdx.x * 256 + threadIdx.x;          // [0, 4096*128)
  int np = i >> 7;                                 // 0..4095
  int k4 = i & 127;                                // 0..127 (float4 index)
  int d  = np >> 11;
  int p  = np & 2047;
  int src = (p & 3) * 512 + (p >> 2);
  const float* wx = d ? Wx_b : Wx_f;
  const float* wh = d ? Wh_b : Wh_f;
  float4 vx = reinterpret_cast<const float4*>(wx + (size_t)src * 512)[k4];
  float4 vh = reinterpret_cast<const float4*>(wh + (size_t)src * 512)[k4];
  ushort4 ox, oh;
  ox.x = f2bf(vx.x); ox.y = f2bf(vx.y); ox.z = f2bf(vx.z); ox.w = f2bf(vx.w);
  oh.x = f2bf(vh.x); oh.y = f2bf(vh.y); oh.z = f2bf(vh.z); oh.w = f2bf(vh.w);
  reinterpret_cast<ushort4*>(wall + (size_t)np * 512)[k4] = ox;
  reinterpret_cast<ushort4*>(whp  + (size_t)np * 512)[k4] = oh;
  if (k4 == 0) bias[np] = d ? (bx_b[src] + bh_b[src]) : (bx_f[src] + bh_f[src]);
}

// ---------- phase 1: xg = xh @ wall^T + bias ----------
// A = xh [32768][512] bf16, B = wall [4096][512] bf16 (NT), C = xg [32768][4096]
// 128x128 tile, 256 threads (4 waves, 2x2 wave grid), BK=32, mfma 16x16x32 bf16
template <bool XGBF16>
__global__ __launch_bounds__(256) void k_gemm_xg(
    const u16* __restrict__ A, const u16* __restrict__ Bw,
    const float* __restrict__ bias,
    float* __restrict__ Cf, u16* __restrict__ Ch) {
  __shared__ __align__(16) u16 lA[128 * 32];
  __shared__ __align__(16) u16 lB[128 * 32];
  const int tid  = threadIdx.x;
  const int lane = tid & 63;
  const int w    = tid >> 6;
  const int wr   = w >> 1, wc = w & 1;
  const size_t brow = (size_t)blockIdx.y * 128;
  const int    bcol = blockIdx.x * 128;

  f32x4 acc[4][4] = {};

  for (int kk = 0; kk < 16; ++kk) {
    const int k0 = kk * 32;
    __syncthreads();  // protect LDS from previous iteration's readers
#pragma unroll
    for (int q = 0; q < 2; ++q) {
      int idx = q * 256 + tid;        // chunk id, 512 chunks of 16B per tile
      int row = idx >> 2, c = idx & 3;
      gload_lds16(A  + (brow + row) * 512 + k0 + c * 8, &lA[idx * 8]);
      gload_lds16(Bw + (size_t)(bcol + row) * 512 + k0 + c * 8, &lB[idx * 8]);
    }
    __syncthreads();

    bf16x8 af[4], bfr[4];
#pragma unroll
    for (int m = 0; m < 4; ++m) {
      int row = wr * 64 + m * 16 + (lane & 15);
      af[m] = ld8(&lA[row * 32 + (lane >> 4) * 8]);
    }
#pragma unroll
    for (int n = 0; n < 4; ++n) {
      int row = wc * 64 + n * 16 + (lane & 15);
      bfr[n] = ld8(&lB[row * 32 + (lane >> 4) * 8]);
    }
#pragma unroll
    for (int m = 0; m < 4; ++m)
#pragma unroll
      for (int n = 0; n < 4; ++n)
        acc[m][n] = __builtin_amdgcn_mfma_f32_16x16x32_bf16(af[m], bfr[n], acc[m][n], 0, 0, 0);
  }

#pragma unroll
  for (int m = 0; m < 4; ++m) {
#pragma unroll
    for (int n = 0; n < 4; ++n) {
      int col = bcol + wc * 64 + n * 16 + (lane & 15);
      float bb = bias[col];
#pragma unroll
      for (int r = 0; r < 4; ++r) {
        size_t row = brow + wr * 64 + m * 16 + (lane >> 4) * 4 + r;
        float v = acc[m][n][r] + bb;
        if (XGBF16) Ch[row * 4096 + col] = f2bf(v);
        else        Cf[row * 4096 + col] = v;
      }
    }
  }
}

// ---------- phase 2: one timestep (both directions), 32 blocks ----------
// block bid: d = bid>>4, ntile = bid&15 -> p-slice [ntile*128, ntile*128+128)
// g[32 x 128] = hprev[32 x 512] @ Whp_slice^T, then gates for j-slice of 32.
template <bool XGBF16>
__global__ __launch_bounds__(256) void k_step(
    const u16* __restrict__ whp,
    const float* __restrict__ xgf, const u16* __restrict__ xgh,
    const u16* __restrict__ hin, u16* __restrict__ hout,
    float* __restrict__ cbuf, float* __restrict__ out,
    float* __restrict__ fh, float* __restrict__ fc, int t) {
  const int tid  = threadIdx.x;
  const int lane = tid & 63;
  const int w    = tid >> 6;
  const int bid  = blockIdx.x;
  const int d     = bid >> 4;
  const int ntile = bid & 15;
  const int sd = d ? (1023 - t) : t;
  const u16* hprev = hin + d * (32 * 512);
  const u16* wbase = whp + (size_t)(d * 2048 + ntile * 128) * 512;

  f32x4 acc[2][2] = {};
#pragma unroll
  for (int kk = 0; kk < 16; ++kk) {
    const int krow = kk * 32 + (lane >> 4) * 8;
    bf16x8 a[2], b[2];
#pragma unroll
    for (int m = 0; m < 2; ++m)
      a[m] = ld8(hprev + (size_t)(m * 16 + (lane & 15)) * 512 + krow);
#pragma unroll
    for (int n = 0; n < 2; ++n)
      b[n] = ld8(wbase + (size_t)(w * 32 + n * 16 + (lane & 15)) * 512 + krow);
#pragma unroll
    for (int m = 0; m < 2; ++m)
#pragma unroll
      for (int n = 0; n < 2; ++n)
        acc[m][n] = __builtin_amdgcn_mfma_f32_16x16x32_bf16(a[m], b[n], acc[m][n], 0, 0, 0);
  }

  __shared__ float gbuf[32][128];
#pragma unroll
  for (int m = 0; m < 2; ++m)
#pragma unroll
    for (int n = 0; n < 2; ++n)
#pragma unroll
      for (int r = 0; r < 4; ++r)
        gbuf[m * 16 + (lane >> 4) * 4 + r][w * 32 + n * 16 + (lane & 15)] = acc[m][n][r];
  __syncthreads();

#pragma unroll
  for (int it = 0; it < 4; ++it) {
    int idx = it * 256 + tid;          // 0..1023
    int b  = idx >> 5;                 // batch 0..31
    int jl = idx & 31;                 // local j
    float4 gv = *reinterpret_cast<const float4*>(&gbuf[b][jl * 4]);
    float xi, xf, xo, xc;
    size_t xoff = ((size_t)(b * 1024 + sd)) * 4096 + (size_t)(d * 2048 + ntile * 128 + jl * 4);
    if (XGBF16) {
      ushort4 xv = *reinterpret_cast<const ushort4*>(xgh + xoff);
      xi = bf2f(xv.x); xf = bf2f(xv.y); xo = bf2f(xv.z); xc = bf2f(xv.w);
    } else {
      float4 xv = *reinterpret_cast<const float4*>(xgf + xoff);
      xi = xv.x; xf = xv.y; xo = xv.z; xc = xv.w;
    }
    float gi = gv.x + xi, gf = gv.y + xf, go = gv.z + xo, gc = gv.w + xc;
    int jg = ntile * 32 + jl;
    float* cp = cbuf + (size_t)(d * 32 + b) * 512 + jg;
    float c_old = *cp;
    float i_g = sigf(gi), f_g = sigf(gf), o_g = sigf(go);
    float cn = f_g * c_old + i_g * tanhf(gc);
    float hn = o_g * tanhf(cn);
    *cp = cn;
    out[((size_t)b * 1024 + sd) * 1024 + d * 512 + jg] = hn;
    hout[d * (32 * 512) + b * 512 + jg] = f2bf(hn);
    if (t == 1023) {
      fh[b * 1024 + d * 512 + jg] = hn;
      fc[b * 1024 + d * 512 + jg] = cn;
    }
  }
}

// ---------- host ----------
extern "C" void kernel_launch(void* const* d_in, const int* in_sizes, int n_in,
                              void* d_out, int out_size, void* d_ws, size_t ws_size,
                              hipStream_t stream) {
  (void)in_sizes; (void)n_in; (void)out_size;
  const float* x    = (const float*)d_in[0];
  const float* Wx_f = (const float*)d_in[1];
  const float* Wh_f = (const float*)d_in[2];
  const float* bx_f = (const float*)d_in[3];
  const float* bh_f = (const float*)d_in[4];
  const float* Wx_b = (const float*)d_in[5];
  const float* Wh_b = (const float*)d_in[6];
  const float* bx_b = (const float*)d_in[7];
  const float* bh_b = (const float*)d_in[8];

  char* ws = (char*)d_ws;
  const size_t XG_F32 = (size_t)32768 * 4096 * 4;   // 512 MB
  const size_t XG_BF  = (size_t)32768 * 4096 * 2;   // 256 MB
  const size_t REST   = 33554432 + 4194304 + 4194304 + 16384 + 131072 + 131072;
  const bool xg_bf16 = (ws_size < XG_F32 + REST);

  size_t off = xg_bf16 ? XG_BF : XG_F32;
  float* xg_f = (float*)ws;
  u16*   xg_h = (u16*)ws;
  u16*   xh   = (u16*)(ws + off);  off += 33554432;   // x as bf16
  u16*   wall = (u16*)(ws + off);  off += 4194304;    // packed Wx (both dirs)
  u16*   whp  = (u16*)(ws + off);  off += 4194304;    // packed Wh (both dirs)
  float* bias = (float*)(ws + off); off += 16384;     // bx+bh packed
  u16*   hbuf = (u16*)(ws + off);  off += 131072;     // [2][2][32][512] bf16
  float* cbuf = (float*)(ws + off); off += 131072;    // [2][32][512] f32

  float* out = (float*)d_out;
  float* fh  = out + (size_t)33554432;
  float* fc  = fh + 32768;

  hipMemsetAsync(hbuf, 0, 131072 + 131072, stream);   // zero h and c state
  k_conv_x<<<16384, 256, 0, stream>>>(x, xh);
  k_pack_w<<<2048, 256, 0, stream>>>(Wx_f, Wh_f, bx_f, bh_f,
                                     Wx_b, Wh_b, bx_b, bh_b, wall, whp, bias);
  if (xg_bf16)
    k_gemm_xg<true><<<dim3(32, 256), 256, 0, stream>>>(xh, wall, bias, nullptr, xg_h);
  else
    k_gemm_xg<false><<<dim3(32, 256), 256, 0, stream>>>(xh, wall, bias, xg_f, nullptr);

  for (int t = 0; t < 1024; ++t) {
    const u16* hin = hbuf + (t & 1) * 32768;
    u16* hout      = hbuf + ((t & 1) ^ 1) * 32768;
    if (xg_bf16)
      k_step<true><<<32, 256, 0, stream>>>(whp, nullptr, xg_h, hin, hout,
                                           cbuf, out, fh, fc, t);
    else
      k_step<false><<<32, 256, 0, stream>>>(whp, xg_f, nullptr, hin, hout,
                                            cbuf, out, fh, fc, t);
  }
}

// Round 2
// 10839.165 us; speedup vs baseline: 1.1933x; 1.1933x over previous
//
#include <hip/hip_runtime.h>

typedef unsigned short u16;
typedef __attribute__((ext_vector_type(8))) short short8v;
typedef __attribute__((ext_vector_type(8))) __bf16 bf16x8;
typedef __attribute__((ext_vector_type(4))) float f32x4;

#define AS1 __attribute__((address_space(1)))
#define AS3 __attribute__((address_space(3)))

// ---------- helpers ----------
__device__ __forceinline__ u16 f2bf(float f) {
  unsigned u = __float_as_uint(f);
  u += 0x7fffu + ((u >> 16) & 1u);   // round-to-nearest-even
  return (u16)(u >> 16);
}
__device__ __forceinline__ float bf2f(u16 h) {
  return __uint_as_float(((unsigned)h) << 16);
}
__device__ __forceinline__ void gload_lds16(const void* g, void* l) {
  __builtin_amdgcn_global_load_lds((const AS1 void*)g, (AS3 void*)l, 16, 0, 0);
}
__device__ __forceinline__ bf16x8 ld8(const u16* p) {
  return __builtin_bit_cast(bf16x8, *reinterpret_cast<const short8v*>(p));
}
__device__ __forceinline__ float sigf(float x) { return 1.0f / (1.0f + __expf(-x)); }
__device__ __forceinline__ float tanhfast(float x) {
  float e = __expf(2.0f * x);
  return 1.0f - 2.0f / (e + 1.0f);
}

// ---------- setup kernels ----------
__global__ __launch_bounds__(256) void k_conv_x(const float* __restrict__ x,
                                                u16* __restrict__ xh) {
  int i = blockIdx.x * 256 + threadIdx.x;
  float4 v = reinterpret_cast<const float4*>(x)[i];
  ushort4 o;
  o.x = f2bf(v.x); o.y = f2bf(v.y); o.z = f2bf(v.z); o.w = f2bf(v.w);
  reinterpret_cast<ushort4*>(xh)[i] = o;
}

// gate-interleaved packing: n' = d*2048 + 4j + g, src row = g*512 + j
__global__ __launch_bounds__(256) void k_pack_w(
    const float* __restrict__ Wx_f, const float* __restrict__ Wh_f,
    const float* __restrict__ bx_f, const float* __restrict__ bh_f,
    const float* __restrict__ Wx_b, const float* __restrict__ Wh_b,
    const float* __restrict__ bx_b, const float* __restrict__ bh_b,
    u16* __restrict__ wall, u16* __restrict__ whp, float* __restrict__ bias) {
  int i = blockIdx.x * 256 + threadIdx.x;
  int np = i >> 7;
  int k4 = i & 127;
  int d  = np >> 11;
  int p  = np & 2047;
  int src = (p & 3) * 512 + (p >> 2);
  const float* wx = d ? Wx_b : Wx_f;
  const float* wh = d ? Wh_b : Wh_f;
  float4 vx = reinterpret_cast<const float4*>(wx + (size_t)src * 512)[k4];
  float4 vh = reinterpret_cast<const float4*>(wh + (size_t)src * 512)[k4];
  ushort4 ox, oh;
  ox.x = f2bf(vx.x); ox.y = f2bf(vx.y); ox.z = f2bf(vx.z); ox.w = f2bf(vx.w);
  oh.x = f2bf(vh.x); oh.y = f2bf(vh.y); oh.z = f2bf(vh.z); oh.w = f2bf(vh.w);
  reinterpret_cast<ushort4*>(wall + (size_t)np * 512)[k4] = ox;
  reinterpret_cast<ushort4*>(whp  + (size_t)np * 512)[k4] = oh;
  if (k4 == 0) bias[np] = d ? (bx_b[src] + bh_b[src]) : (bx_f[src] + bh_f[src]);
}

// ---------- phase 1: xg = xh @ wall^T + bias ----------
template <bool XGBF16>
__global__ __launch_bounds__(256) void k_gemm_xg(
    const u16* __restrict__ A, const u16* __restrict__ Bw,
    const float* __restrict__ bias,
    float* __restrict__ Cf, u16* __restrict__ Ch) {
  __shared__ __align__(16) u16 lA[128 * 32];
  __shared__ __align__(16) u16 lB[128 * 32];
  const int tid  = threadIdx.x;
  const int lane = tid & 63;
  const int w    = tid >> 6;
  const int wr   = w >> 1, wc = w & 1;
  const size_t brow = (size_t)blockIdx.y * 128;
  const int    bcol = blockIdx.x * 128;

  f32x4 acc[4][4] = {};

  for (int kk = 0; kk < 16; ++kk) {
    const int k0 = kk * 32;
    __syncthreads();
#pragma unroll
    for (int q = 0; q < 2; ++q) {
      int idx = q * 256 + tid;
      int row = idx >> 2, c = idx & 3;
      gload_lds16(A  + (brow + row) * 512 + k0 + c * 8, &lA[idx * 8]);
      gload_lds16(Bw + (size_t)(bcol + row) * 512 + k0 + c * 8, &lB[idx * 8]);
    }
    __syncthreads();

    bf16x8 af[4], bfr[4];
#pragma unroll
    for (int m = 0; m < 4; ++m) {
      int row = wr * 64 + m * 16 + (lane & 15);
      af[m] = ld8(&lA[row * 32 + (lane >> 4) * 8]);
    }
#pragma unroll
    for (int n = 0; n < 4; ++n) {
      int row = wc * 64 + n * 16 + (lane & 15);
      bfr[n] = ld8(&lB[row * 32 + (lane >> 4) * 8]);
    }
#pragma unroll
    for (int m = 0; m < 4; ++m)
#pragma unroll
      for (int n = 0; n < 4; ++n)
        acc[m][n] = __builtin_amdgcn_mfma_f32_16x16x32_bf16(af[m], bfr[n], acc[m][n], 0, 0, 0);
  }

#pragma unroll
  for (int m = 0; m < 4; ++m) {
#pragma unroll
    for (int n = 0; n < 4; ++n) {
      int col = bcol + wc * 64 + n * 16 + (lane & 15);
      float bb = bias[col];
#pragma unroll
      for (int r = 0; r < 4; ++r) {
        size_t row = brow + wr * 64 + m * 16 + (lane >> 4) * 4 + r;
        float v = acc[m][n][r] + bb;
        if (XGBF16) Ch[row * 4096 + col] = f2bf(v);
        else        Cf[row * 4096 + col] = v;
      }
    }
  }
}

// ---------- phase 2: persistent recurrence kernel ----------
// 32 blocks: d = bid>>4, ntile = bid&15 -> 128 p-cols per block.
// Wh slice held in registers (32 bf16x8 frags/thread). One device-scope
// barrier per step per direction (monotonic counter, fan-in 16).
template <bool XGBF16>
__global__ __launch_bounds__(256, 1) void k_rnn(
    const u16* __restrict__ whp,
    const float* __restrict__ xgf, const u16* __restrict__ xgh,
    u16* __restrict__ hbuf, float* __restrict__ out,
    float* __restrict__ fh, float* __restrict__ fc,
    unsigned* ctr) {
  const int tid  = threadIdx.x;
  const int lane = tid & 63;
  const int w    = tid >> 6;
  const int bid  = blockIdx.x;
  const int d     = bid >> 4;
  const int ntile = bid & 15;

  // ---- load Wh slice into registers (once) ----
  const u16* wbase = whp + (size_t)(d * 2048 + ntile * 128 + w * 32) * 512;
  bf16x8 wf[16][2];
#pragma unroll
  for (int kk = 0; kk < 16; ++kk)
#pragma unroll
    for (int n = 0; n < 2; ++n)
      wf[kk][n] = ld8(wbase + (size_t)(n * 16 + (lane & 15)) * 512 + kk * 32 + (lane >> 4) * 8);

  unsigned* myctr = ctr + d * 32;   // 128 B apart

  // gate-stage mapping: it in 0..3 -> b = it*8 + (tid>>5), jl = tid&31
  const int brow = tid >> 5;        // 0..7
  const int jl   = tid & 31;
  const int jg   = ntile * 32 + jl;
  const int colbase = d * 2048 + ntile * 128 + jl * 4;

  float cst[4] = {0.f, 0.f, 0.f, 0.f};
  __shared__ float gbuf[32][128];

  for (int t = 0; t < 1024; ++t) {
    const int sd = d ? (1023 - t) : t;

    // prefetch xg for this step (independent of h; overlaps barrier spin)
    float xi[4], xf_[4], xo[4], xc[4];
#pragma unroll
    for (int it = 0; it < 4; ++it) {
      int b = it * 8 + brow;
      size_t xoff = ((size_t)(b * 1024 + sd)) * 4096 + colbase;
      if (XGBF16) {
        ushort4 v = *reinterpret_cast<const ushort4*>(xgh + xoff);
        xi[it] = bf2f(v.x); xf_[it] = bf2f(v.y); xo[it] = bf2f(v.z); xc[it] = bf2f(v.w);
      } else {
        float4 v = *reinterpret_cast<const float4*>(xgf + xoff);
        xi[it] = v.x; xf_[it] = v.y; xo[it] = v.z; xc[it] = v.w;
      }
    }

    if (t > 0) {
      if (tid == 0) {
        while (__hip_atomic_load(myctr, __ATOMIC_RELAXED, __HIP_MEMORY_SCOPE_AGENT)
               < 16u * (unsigned)t)
          __builtin_amdgcn_s_sleep(1);
      }
      __syncthreads();
      __threadfence();   // acquire side: invalidate stale L1/L2 before h reads
    }

    const u16* hin = hbuf + (t & 1) * 32768 + d * 16384;
    f32x4 acc[2][2] = {};
#pragma unroll
    for (int kk = 0; kk < 16; ++kk) {
      const int krow = kk * 32 + (lane >> 4) * 8;
      bf16x8 a0 = ld8(hin + (size_t)(lane & 15) * 512 + krow);
      bf16x8 a1 = ld8(hin + (size_t)(16 + (lane & 15)) * 512 + krow);
#pragma unroll
      for (int n = 0; n < 2; ++n) {
        acc[0][n] = __builtin_amdgcn_mfma_f32_16x16x32_bf16(a0, wf[kk][n], acc[0][n], 0, 0, 0);
        acc[1][n] = __builtin_amdgcn_mfma_f32_16x16x32_bf16(a1, wf[kk][n], acc[1][n], 0, 0, 0);
      }
    }

    // stage g to LDS for gate repartition
#pragma unroll
    for (int m = 0; m < 2; ++m)
#pragma unroll
      for (int n = 0; n < 2; ++n)
#pragma unroll
        for (int r = 0; r < 4; ++r)
          gbuf[m * 16 + (lane >> 4) * 4 + r][w * 32 + n * 16 + (lane & 15)] = acc[m][n][r];
    __syncthreads();

    u16* hout = hbuf + ((t + 1) & 1) * 32768 + d * 16384;
#pragma unroll
    for (int it = 0; it < 4; ++it) {
      int b = it * 8 + brow;
      float4 gv = *reinterpret_cast<const float4*>(&gbuf[b][jl * 4]);
      float gi = gv.x + xi[it], gf = gv.y + xf_[it];
      float go = gv.z + xo[it], gc = gv.w + xc[it];
      float ig = sigf(gi), fg = sigf(gf), og = sigf(go);
      float cn = fg * cst[it] + ig * tanhfast(gc);
      float hn = og * tanhfast(cn);
      cst[it] = cn;
      hout[b * 512 + jg] = f2bf(hn);
      out[((size_t)(b * 1024 + sd)) * 1024 + d * 512 + jg] = hn;
      if (t == 1023) {
        fh[b * 1024 + d * 512 + jg] = hn;
        fc[b * 1024 + d * 512 + jg] = cn;
      }
    }

    __threadfence();   // release side: flush h writes toward coherence point
    __syncthreads();   // all block threads done (stores drained by barrier)
    if (tid == 0)
      __hip_atomic_fetch_add(myctr, 1u, __ATOMIC_RELAXED, __HIP_MEMORY_SCOPE_AGENT);
  }
}

// ---------- host ----------
extern "C" void kernel_launch(void* const* d_in, const int* in_sizes, int n_in,
                              void* d_out, int out_size, void* d_ws, size_t ws_size,
                              hipStream_t stream) {
  (void)in_sizes; (void)n_in; (void)out_size;
  const float* x    = (const float*)d_in[0];
  const float* Wx_f = (const float*)d_in[1];
  const float* Wh_f = (const float*)d_in[2];
  const float* bx_f = (const float*)d_in[3];
  const float* bh_f = (const float*)d_in[4];
  const float* Wx_b = (const float*)d_in[5];
  const float* Wh_b = (const float*)d_in[6];
  const float* bx_b = (const float*)d_in[7];
  const float* bh_b = (const float*)d_in[8];

  char* ws = (char*)d_ws;
  const size_t XG_F32 = (size_t)32768 * 4096 * 4;   // 512 MB
  const size_t XG_BF  = (size_t)32768 * 4096 * 2;   // 256 MB
  const size_t REST   = 33554432 + 4194304 + 4194304 + 16384 + 131072 + 256;
  const bool xg_bf16 = (ws_size < XG_F32 + REST);

  size_t off = xg_bf16 ? XG_BF : XG_F32;
  float* xg_f = (float*)ws;
  u16*   xg_h = (u16*)ws;
  u16*   xh   = (u16*)(ws + off);  off += 33554432;   // x as bf16
  u16*   wall = (u16*)(ws + off);  off += 4194304;    // packed Wx (both dirs)
  u16*   whp  = (u16*)(ws + off);  off += 4194304;    // packed Wh (both dirs)
  float* bias = (float*)(ws + off); off += 16384;     // bx+bh packed
  u16*   hbuf = (u16*)(ws + off);  off += 131072;     // [2 pingpong][2 dir][32][512] bf16
  unsigned* ctr = (unsigned*)(ws + off); off += 256;  // per-dir barrier counters

  float* out = (float*)d_out;
  float* fh  = out + (size_t)33554432;
  float* fc  = fh + 32768;

  hipMemsetAsync(hbuf, 0, 131072 + 256, stream);      // zero h state + barrier ctrs
  k_conv_x<<<16384, 256, 0, stream>>>(x, xh);
  k_pack_w<<<2048, 256, 0, stream>>>(Wx_f, Wh_f, bx_f, bh_f,
                                     Wx_b, Wh_b, bx_b, bh_b, wall, whp, bias);
  if (xg_bf16) {
    k_gemm_xg<true><<<dim3(32, 256), 256, 0, stream>>>(xh, wall, bias, nullptr, xg_h);
    k_rnn<true><<<32, 256, 0, stream>>>(whp, nullptr, xg_h, hbuf, out, fh, fc, ctr);
  } else {
    k_gemm_xg<false><<<dim3(32, 256), 256, 0, stream>>>(xh, wall, bias, xg_f, nullptr);
    k_rnn<false><<<32, 256, 0, stream>>>(whp, xg_f, nullptr, hbuf, out, fh, fc, ctr);
  }
}

// Round 3
// 3927.398 us; speedup vs baseline: 3.2932x; 2.7599x over previous
//
#include <hip/hip_runtime.h>

typedef unsigned short u16;
typedef unsigned int u32;
typedef unsigned long long u64;
typedef __attribute__((ext_vector_type(8))) short short8v;
typedef __attribute__((ext_vector_type(8))) __bf16 bf16x8;
typedef __attribute__((ext_vector_type(4))) float f32x4;
typedef __attribute__((ext_vector_type(2))) float f32x2;

#define AS1 __attribute__((address_space(1)))
#define AS3 __attribute__((address_space(3)))

// ---------- helpers ----------
__device__ __forceinline__ u16 f2bf(float f) {
  unsigned u = __float_as_uint(f);
  u += 0x7fffu + ((u >> 16) & 1u);   // round-to-nearest-even
  return (u16)(u >> 16);
}
__device__ __forceinline__ float bf2f(u16 h) {
  return __uint_as_float(((unsigned)h) << 16);
}
__device__ __forceinline__ void gload_lds16(const void* g, void* l) {
  __builtin_amdgcn_global_load_lds((const AS1 void*)g, (AS3 void*)l, 16, 0, 0);
}
__device__ __forceinline__ bf16x8 ld8(const u16* p) {
  return __builtin_bit_cast(bf16x8, *reinterpret_cast<const short8v*>(p));
}
__device__ __forceinline__ float sigf(float x) { return 1.0f / (1.0f + __expf(-x)); }
__device__ __forceinline__ float tanhfast(float x) {
  float e = __expf(2.0f * x);
  return 1.0f - 2.0f / (e + 1.0f);
}

// ---------- setup kernels ----------
__global__ __launch_bounds__(256) void k_conv_x(const float* __restrict__ x,
                                                u16* __restrict__ xh) {
  int i = blockIdx.x * 256 + threadIdx.x;
  float4 v = reinterpret_cast<const float4*>(x)[i];
  ushort4 o;
  o.x = f2bf(v.x); o.y = f2bf(v.y); o.z = f2bf(v.z); o.w = f2bf(v.w);
  reinterpret_cast<ushort4*>(xh)[i] = o;
}

// gate-interleaved packing: n' = d*2048 + 4j + g, src row = g*512 + j
__global__ __launch_bounds__(256) void k_pack_w(
    const float* __restrict__ Wx_f, const float* __restrict__ Wh_f,
    const float* __restrict__ bx_f, const float* __restrict__ bh_f,
    const float* __restrict__ Wx_b, const float* __restrict__ Wh_b,
    const float* __restrict__ bx_b, const float* __restrict__ bh_b,
    u16* __restrict__ wall, u16* __restrict__ whp, float* __restrict__ bias) {
  int i = blockIdx.x * 256 + threadIdx.x;
  int np = i >> 7;
  int k4 = i & 127;
  int d  = np >> 11;
  int p  = np & 2047;
  int src = (p & 3) * 512 + (p >> 2);
  const float* wx = d ? Wx_b : Wx_f;
  const float* wh = d ? Wh_b : Wh_f;
  float4 vx = reinterpret_cast<const float4*>(wx + (size_t)src * 512)[k4];
  float4 vh = reinterpret_cast<const float4*>(wh + (size_t)src * 512)[k4];
  ushort4 ox, oh;
  ox.x = f2bf(vx.x); ox.y = f2bf(vx.y); ox.z = f2bf(vx.z); ox.w = f2bf(vx.w);
  oh.x = f2bf(vh.x); oh.y = f2bf(vh.y); oh.z = f2bf(vh.z); oh.w = f2bf(vh.w);
  reinterpret_cast<ushort4*>(wall + (size_t)np * 512)[k4] = ox;
  reinterpret_cast<ushort4*>(whp  + (size_t)np * 512)[k4] = oh;
  if (k4 == 0) bias[np] = d ? (bx_b[src] + bh_b[src]) : (bx_f[src] + bh_f[src]);
}

// ---------- phase 1: xg = xh @ wall^T + bias ----------
template <bool XGBF16>
__global__ __launch_bounds__(256) void k_gemm_xg(
    const u16* __restrict__ A, const u16* __restrict__ Bw,
    const float* __restrict__ bias,
    float* __restrict__ Cf, u16* __restrict__ Ch) {
  __shared__ __align__(16) u16 lA[128 * 32];
  __shared__ __align__(16) u16 lB[128 * 32];
  const int tid  = threadIdx.x;
  const int lane = tid & 63;
  const int w    = tid >> 6;
  const int wr   = w >> 1, wc = w & 1;
  const size_t brow = (size_t)blockIdx.y * 128;
  const int    bcol = blockIdx.x * 128;

  f32x4 acc[4][4] = {};

  for (int kk = 0; kk < 16; ++kk) {
    const int k0 = kk * 32;
    __syncthreads();
#pragma unroll
    for (int q = 0; q < 2; ++q) {
      int idx = q * 256 + tid;
      int row = idx >> 2, c = idx & 3;
      gload_lds16(A  + (brow + row) * 512 + k0 + c * 8, &lA[idx * 8]);
      gload_lds16(Bw + (size_t)(bcol + row) * 512 + k0 + c * 8, &lB[idx * 8]);
    }
    __syncthreads();

    bf16x8 af[4], bfr[4];
#pragma unroll
    for (int m = 0; m < 4; ++m) {
      int row = wr * 64 + m * 16 + (lane & 15);
      af[m] = ld8(&lA[row * 32 + (lane >> 4) * 8]);
    }
#pragma unroll
    for (int n = 0; n < 4; ++n) {
      int row = wc * 64 + n * 16 + (lane & 15);
      bfr[n] = ld8(&lB[row * 32 + (lane >> 4) * 8]);
    }
#pragma unroll
    for (int m = 0; m < 4; ++m)
#pragma unroll
      for (int n = 0; n < 4; ++n)
        acc[m][n] = __builtin_amdgcn_mfma_f32_16x16x32_bf16(af[m], bfr[n], acc[m][n], 0, 0, 0);
  }

#pragma unroll
  for (int m = 0; m < 4; ++m) {
#pragma unroll
    for (int n = 0; n < 4; ++n) {
      int col = bcol + wc * 64 + n * 16 + (lane & 15);
      float bb = bias[col];
#pragma unroll
      for (int r = 0; r < 4; ++r) {
        size_t row = brow + wr * 64 + m * 16 + (lane >> 4) * 4 + r;
        float v = acc[m][n][r] + bb;
        if (XGBF16) Ch[row * 4096 + col] = f2bf(v);
        else        Cf[row * 4096 + col] = v;
      }
    }
  }
}

// ---------- phase 2: persistent recurrence, fence-free sc1 exchange ----------
// 32 blocks: d = bid>>4, ntile = bid&15 (128 gate-cols per block).
// h exchanged as packed u32 pairs via agent-scope relaxed atomics (coherent at
// LLC, no cache-wide fences). Per-block arrival flags (store, not RMW); all
// threads spin, one flag per lane. h staged to LDS with q^=(row&7) swizzle so
// ds_read_b128 fragment reads hit the 8-phase optimum.
template <bool XGBF16>
__global__ __launch_bounds__(256, 1) void k_rnn(
    const u16* __restrict__ whp,
    const float* __restrict__ xgf, const u16* __restrict__ xgh,
    u32* __restrict__ hbuf, u32* __restrict__ flags,
    float* __restrict__ out, float* __restrict__ fh, float* __restrict__ fc) {
  const int tid  = threadIdx.x;
  const int lane = tid & 63;
  const int w    = tid >> 6;
  const int bid  = (int)blockIdx.x;
  const int d     = bid >> 4;
  const int ntile = bid & 15;

  __shared__ __align__(16) u64 hlds[4096];          // 32 KB staged h (swizzled)
  __shared__ __align__(16) float gbuf[32][132];     // padded: 2-way max

  // ---- Wh slice -> registers (once) ----
  const u16* wbase = whp + (size_t)(d * 2048 + ntile * 128 + w * 32) * 512;
  bf16x8 wf[16][2];
#pragma unroll
  for (int kk = 0; kk < 16; ++kk)
#pragma unroll
    for (int n = 0; n < 2; ++n)
      wf[kk][n] = ld8(wbase + (size_t)(n * 16 + (lane & 15)) * 512 + kk * 32 + (lane >> 4) * 8);

  // gate-phase mapping: thread = (brow 0..15, jp 0..15); it in {0,1} -> b = it*16+brow
  const int brow = tid >> 4;
  const int jp   = tid & 15;
  const int colbase = d * 2048 + ntile * 128 + jp * 8;

  float cst[2][2] = {{0.f, 0.f}, {0.f, 0.f}};

  const int FSTR = 64;                              // u32 stride between flags (256 B)
  u32* myflag = flags + (d * 16 + ntile) * FSTR;
  u32* spinflag = flags + (d * 16 + (tid & 15)) * FSTR;

  const int r0 = lane & 15;
  const int qb = lane >> 4;
  const int swz = lane & 7;

  for (int t = 0; t < 1024; ++t) {
    const int sd = d ? (1023 - t) : t;

    // ---- xg prefetch (regular cached loads; overlaps the spin) ----
    short8v xh0, xh1;
    float4 xf0a, xf0b, xf1a, xf1b;
    {
      size_t xoff0 = ((size_t)(brow * 1024 + sd)) * 4096 + colbase;
      size_t xoff1 = ((size_t)((16 + brow) * 1024 + sd)) * 4096 + colbase;
      if (XGBF16) {
        xh0 = *reinterpret_cast<const short8v*>(xgh + xoff0);
        xh1 = *reinterpret_cast<const short8v*>(xgh + xoff1);
      } else {
        xf0a = *reinterpret_cast<const float4*>(xgf + xoff0);
        xf0b = *reinterpret_cast<const float4*>(xgf + xoff0 + 4);
        xf1a = *reinterpret_cast<const float4*>(xgf + xoff1);
        xf1b = *reinterpret_cast<const float4*>(xgf + xoff1 + 4);
      }
    }

    // ---- wait for all 16 producer blocks of this direction ----
    if (t > 0) {
      while (__hip_atomic_load(spinflag, __ATOMIC_RELAXED, __HIP_MEMORY_SCOPE_AGENT) < (u32)t)
        __builtin_amdgcn_s_sleep(1);
      asm volatile("" ::: "memory");
    }

    // ---- stage h (coherent u64 loads -> swizzled LDS) ----
    const u64* hg = (const u64*)hbuf + ((size_t)(t & 1) * 2 + d) * 4096;
    u64 vtmp[16];
#pragma unroll
    for (int p = 0; p < 16; ++p)
      vtmp[p] = __hip_atomic_load(hg + p * 256 + tid, __ATOMIC_RELAXED, __HIP_MEMORY_SCOPE_AGENT);
#pragma unroll
    for (int p = 0; p < 16; ++p) {
      int i = p * 256 + tid;
      int b = i >> 7, u = i & 127;
      int q = (u >> 1) ^ (b & 7);
      hlds[b * 128 + q * 2 + (u & 1)] = vtmp[p];
    }
    __syncthreads();

    // ---- g = h @ Wh_slice^T (MFMA) ----
    f32x4 acc[2][2] = {};
#pragma unroll
    for (int kk = 0; kk < 16; ++kk) {
      int q = kk * 4 + qb;
      bf16x8 a0 = *reinterpret_cast<const bf16x8*>(
          (const char*)hlds + ((size_t)r0 * 64 + (q ^ swz)) * 16);
      bf16x8 a1 = *reinterpret_cast<const bf16x8*>(
          (const char*)hlds + ((size_t)(16 + r0) * 64 + (q ^ swz)) * 16);
#pragma unroll
      for (int n = 0; n < 2; ++n) {
        acc[0][n] = __builtin_amdgcn_mfma_f32_16x16x32_bf16(a0, wf[kk][n], acc[0][n], 0, 0, 0);
        acc[1][n] = __builtin_amdgcn_mfma_f32_16x16x32_bf16(a1, wf[kk][n], acc[1][n], 0, 0, 0);
      }
    }

    // ---- stage g to LDS for gate repartition ----
#pragma unroll
    for (int m = 0; m < 2; ++m)
#pragma unroll
      for (int n = 0; n < 2; ++n)
#pragma unroll
        for (int r = 0; r < 4; ++r)
          gbuf[m * 16 + qb * 4 + r][w * 32 + n * 16 + r0] = acc[m][n][r];
    __syncthreads();

    // ---- gates, cell update, h/out stores ----
    u32* hdst = hbuf + ((size_t)((t + 1) & 1) * 2 + d) * 8192;
#pragma unroll
    for (int it = 0; it < 2; ++it) {
      int b = it * 16 + brow;
      float4 g0 = *reinterpret_cast<const float4*>(&gbuf[b][jp * 8]);
      float4 g1 = *reinterpret_cast<const float4*>(&gbuf[b][jp * 8 + 4]);
      float xi0, xff0, xo0, xc0, xi1, xff1, xo1, xc1;
      if (XGBF16) {
        const short8v& xv = it ? xh1 : xh0;
        xi0 = bf2f((u16)xv[0]); xff0 = bf2f((u16)xv[1]);
        xo0 = bf2f((u16)xv[2]); xc0  = bf2f((u16)xv[3]);
        xi1 = bf2f((u16)xv[4]); xff1 = bf2f((u16)xv[5]);
        xo1 = bf2f((u16)xv[6]); xc1  = bf2f((u16)xv[7]);
      } else {
        const float4& va = it ? xf1a : xf0a;
        const float4& vb = it ? xf1b : xf0b;
        xi0 = va.x; xff0 = va.y; xo0 = va.z; xc0 = va.w;
        xi1 = vb.x; xff1 = vb.y; xo1 = vb.z; xc1 = vb.w;
      }
      float gi0 = g0.x + xi0, gf0 = g0.y + xff0, go0 = g0.z + xo0, gc0 = g0.w + xc0;
      float gi1 = g1.x + xi1, gf1 = g1.y + xff1, go1 = g1.z + xo1, gc1 = g1.w + xc1;
      float cn0 = sigf(gf0) * cst[it][0] + sigf(gi0) * tanhfast(gc0);
      float cn1 = sigf(gf1) * cst[it][1] + sigf(gi1) * tanhfast(gc1);
      float hn0 = sigf(go0) * tanhfast(cn0);
      float hn1 = sigf(go1) * tanhfast(cn1);
      cst[it][0] = cn0; cst[it][1] = cn1;

      u32 pack = (u32)f2bf(hn0) | ((u32)f2bf(hn1) << 16);
      __hip_atomic_store(hdst + b * 256 + ntile * 16 + jp, pack,
                         __ATOMIC_RELAXED, __HIP_MEMORY_SCOPE_AGENT);
      f32x2 ov; ov.x = hn0; ov.y = hn1;
      __builtin_nontemporal_store(ov, reinterpret_cast<f32x2*>(
          out + ((size_t)(b * 1024 + sd)) * 1024 + d * 512 + ntile * 32 + jp * 2));
      if (t == 1023) {
        int fo = b * 1024 + d * 512 + ntile * 32 + jp * 2;
        f32x2 hv; hv.x = hn0; hv.y = hn1;
        f32x2 cv; cv.x = cn0; cv.y = cn1;
        *reinterpret_cast<f32x2*>(fh + fo) = hv;
        *reinterpret_cast<f32x2*>(fc + fo) = cv;
      }
    }

    // ---- publish: drain stores (wave-level), block barrier, flag ----
    asm volatile("s_waitcnt vmcnt(0)" ::: "memory");
    __syncthreads();
    if (tid == 0)
      __hip_atomic_store(myflag, (u32)(t + 1), __ATOMIC_RELAXED, __HIP_MEMORY_SCOPE_AGENT);
  }
}

// ---------- host ----------
extern "C" void kernel_launch(void* const* d_in, const int* in_sizes, int n_in,
                              void* d_out, int out_size, void* d_ws, size_t ws_size,
                              hipStream_t stream) {
  (void)in_sizes; (void)n_in; (void)out_size;
  const float* x    = (const float*)d_in[0];
  const float* Wx_f = (const float*)d_in[1];
  const float* Wh_f = (const float*)d_in[2];
  const float* bx_f = (const float*)d_in[3];
  const float* bh_f = (const float*)d_in[4];
  const float* Wx_b = (const float*)d_in[5];
  const float* Wh_b = (const float*)d_in[6];
  const float* bx_b = (const float*)d_in[7];
  const float* bh_b = (const float*)d_in[8];

  char* ws = (char*)d_ws;
  const size_t XG_F32 = (size_t)32768 * 4096 * 4;   // 512 MB
  const size_t XG_BF  = (size_t)32768 * 4096 * 2;   // 256 MB
  const size_t REST   = 33554432 + 4194304 + 4194304 + 16384 + 262144 + 16384;
  const bool xg_bf16 = (ws_size < XG_F32 + REST);

  size_t off = xg_bf16 ? XG_BF : XG_F32;
  float* xg_f = (float*)ws;
  u16*   xg_h = (u16*)ws;
  u16*   xh   = (u16*)(ws + off);  off += 33554432;   // x as bf16
  u16*   wall = (u16*)(ws + off);  off += 4194304;    // packed Wx (both dirs)
  u16*   whp  = (u16*)(ws + off);  off += 4194304;    // packed Wh (both dirs)
  float* bias = (float*)(ws + off); off += 16384;     // bx+bh packed
  u32*   hbuf = (u32*)(ws + off);  off += 262144;     // [2 pp][2 dir][32][256] u32
  u32*   flags = (u32*)(ws + off); off += 16384;      // 32 flags, 256 B apart

  float* out = (float*)d_out;
  float* fh  = out + (size_t)33554432;
  float* fc  = fh + 32768;

  hipMemsetAsync(hbuf, 0, 262144 + 16384, stream);    // zero h state + flags
  k_conv_x<<<16384, 256, 0, stream>>>(x, xh);
  k_pack_w<<<2048, 256, 0, stream>>>(Wx_f, Wh_f, bx_f, bh_f,
                                     Wx_b, Wh_b, bx_b, bh_b, wall, whp, bias);
  if (xg_bf16) {
    k_gemm_xg<true><<<dim3(32, 256), 256, 0, stream>>>(xh, wall, bias, nullptr, xg_h);
    k_rnn<true><<<32, 256, 0, stream>>>(whp, nullptr, xg_h, hbuf, flags, out, fh, fc);
  } else {
    k_gemm_xg<false><<<dim3(32, 256), 256, 0, stream>>>(xh, wall, bias, xg_f, nullptr);
    k_rnn<false><<<32, 256, 0, stream>>>(whp, xg_f, nullptr, hbuf, flags, out, fh, fc);
  }
}